// Round 7
// baseline (910.842 us; speedup 1.0000x reference)
//
#include <hip/hip_runtime.h>
#include <math.h>

#define NB 2048
#define ND 512
#define NG 8
#define NITER 64

typedef _Float16 h8 __attribute__((ext_vector_type(8)));
typedef short bf16x8 __attribute__((ext_vector_type(8)));
typedef short us4 __attribute__((ext_vector_type(4)));
typedef float f32x4 __attribute__((ext_vector_type(4)));

#define LOG2E 1.4426950408889634f
#define LN2   0.6931471805599453f
#define NEGINF (-__builtin_inff())
#define L2_09 -0.15200309344504997f  /* log2(0.9) */

__device__ __forceinline__ float fexp2(float x) { return __builtin_amdgcn_exp2f(x); }
__device__ __forceinline__ float flog2(float x) { return __builtin_amdgcn_logf(x); }

__device__ __forceinline__ unsigned short f2bf(float x) {
  unsigned u = __float_as_uint(x);
  unsigned r = u + 0x7fff + ((u >> 16) & 1);
  return (unsigned short)(r >> 16);
}
__device__ __forceinline__ float bf2f(unsigned short h) {
  return __uint_as_float(((unsigned)h) << 16);
}

__device__ __forceinline__ void online1(float& m, float& s, float t) {
  float M = fmaxf(m, t);
  s = fmaf(s, fexp2(m - M), fexp2(t - M));
  m = M;
}
__device__ __forceinline__ float wave_max(float v) {
  #pragma unroll
  for (int o = 32; o; o >>= 1) v = fmaxf(v, __shfl_xor(v, o));
  return v;
}
__device__ __forceinline__ float wave_sum(float v) {
  #pragma unroll
  for (int o = 32; o; o >>= 1) v += __shfl_xor(v, o);
  return v;
}

// ---- inline eps schedule ----
__device__ __forceinline__ float eps_at(const unsigned int* cmax, int t) {
  float cm = __uint_as_float(*cmax);
  float diam = sqrtf(2.f * fmaxf(cm, 1e-12f));
  float sig = fmaxf(diam * fexp2((float)t * L2_09), 0.05f);
  return sig * sig;
}

// ---- setup: O(N) stable counting sort via packed 16-bit scan ----
__global__ __launch_bounds__(256) void k_setup(
    const int* __restrict__ sub_raw,
    int* __restrict__ order, int* __restrict__ pgroup,
    int* __restrict__ counts, int* __restrict__ starts,
    float* __restrict__ lc2, unsigned int* __restrict__ cmax,
    float* __restrict__ gpot, float* __restrict__ f,
    float* __restrict__ fxx0, float* __restrict__ fyy0) {
  __shared__ int subs[NB];
  __shared__ unsigned long long scanLo[256], scanHi[256];
  __shared__ int st[NG + 1];
  __shared__ int odd_nz;
  const int t = threadIdx.x;
  if (t == 0) odd_nz = 0;
  __syncthreads();
  int nz = 0;
  for (int k = t; k < 1024; k += 256) nz |= (sub_raw[2 * k + 1] != 0) ? 1 : 0;
  if (nz) atomicOr(&odd_nz, 1);
  __syncthreads();
  const int stride = odd_nz ? 1 : 2;
  for (int i = t; i < NB; i += 256) subs[i] = sub_raw[(size_t)i * stride] & 7;
  __syncthreads();
  unsigned long long cLo = 0ull, cHi = 0ull;
  #pragma unroll
  for (int k = 0; k < 8; ++k) {
    int g = subs[8 * t + k];
    unsigned long long inc = 1ull << ((g & 3) * 16);
    if (g < 4) cLo += inc; else cHi += inc;
  }
  scanLo[t] = cLo; scanHi[t] = cHi;
  __syncthreads();
  for (int s = 1; s < 256; s <<= 1) {
    unsigned long long aLo = (t >= s) ? scanLo[t - s] : 0ull;
    unsigned long long aHi = (t >= s) ? scanHi[t - s] : 0ull;
    __syncthreads();
    scanLo[t] += aLo; scanHi[t] += aHi;
    __syncthreads();
  }
  if (t == 0) {
    unsigned long long TLo = scanLo[255], THi = scanHi[255];
    int a = 0;
    for (int g = 0; g < NG; ++g) {
      st[g] = a;
      a += (int)(((g < 4 ? TLo : THi) >> ((g & 3) * 16)) & 0xffffull);
    }
    st[NG] = a;
  }
  __syncthreads();
  unsigned long long bLo = t ? scanLo[t - 1] : 0ull;
  unsigned long long bHi = t ? scanHi[t - 1] : 0ull;
  #pragma unroll
  for (int k = 0; k < 8; ++k) {
    int idx = 8 * t + k;
    int g = subs[idx];
    int sh = (g & 3) * 16;
    unsigned long long cur = (g < 4) ? bLo : bHi;
    int r = (int)((cur >> sh) & 0xffffull);
    int pos = st[g] + r;
    order[pos] = idx;
    pgroup[pos] = g;
    if (g < 4) bLo += 1ull << sh; else bHi += 1ull << sh;
  }
  if (t < NG) {
    int c = st[t + 1] - st[t];
    counts[t] = c;
    int cc = c < 1 ? 1 : c;
    lc2[t] = -flog2((float)cc);
  }
  if (t < NG + 1) starts[t] = st[t];
  if (t == 0) *cmax = 0u;
  {
    float4* g4 = (float4*)gpot;
    for (int i = t; i < NG * NB / 4; i += 256) g4[i] = make_float4(0.f, 0.f, 0.f, 0.f);
  }
  for (int i = t; i < NB; i += 256) { f[i] = 0.f; fxx0[i] = 0.f; fyy0[i] = 0.f; }
}

// ---- permute + split into bf16 hi/lo + row norms (norms from exact f32) ----
__global__ __launch_bounds__(128) void k_permute(
    const float* __restrict__ X, const int* __restrict__ order,
    unsigned short* __restrict__ Xhi, unsigned short* __restrict__ Xlo,
    float* __restrict__ norms) {
  const int i = blockIdx.x, t = threadIdx.x;
  const int src = order[i];
  float4 v = ((const float4*)(X + (size_t)src * ND))[t];
  float vv[4] = {v.x, v.y, v.z, v.w};
  unsigned short h[4], l[4];
  #pragma unroll
  for (int e = 0; e < 4; ++e) {
    h[e] = f2bf(vv[e]);
    l[e] = f2bf(vv[e] - bf2f(h[e]));
  }
  us4 hv = { (short)h[0], (short)h[1], (short)h[2], (short)h[3] };
  us4 lv = { (short)l[0], (short)l[1], (short)l[2], (short)l[3] };
  *(us4*)(Xhi + (size_t)i * ND + t * 4) = hv;
  *(us4*)(Xlo + (size_t)i * ND + t * 4) = lv;
  float ss = v.x * v.x + v.y * v.y + v.z * v.z + v.w * v.w;
  #pragma unroll
  for (int o = 32; o; o >>= 1) ss += __shfl_xor(ss, o);
  __shared__ float p[2];
  if ((t & 63) == 0) p[t >> 6] = ss;
  __syncthreads();
  if (t == 0) norms[i] = p[0] + p[1];
}

// ---- C = fp16(0.5*relu(n_i + n_j - 2 X X^T)) via split-bf16 MFMA + global max ----
__global__ __launch_bounds__(256, 1) void k_gemm(
    const unsigned short* __restrict__ Xhi, const unsigned short* __restrict__ Xlo,
    const float* __restrict__ norms, _Float16* __restrict__ C,
    unsigned int* __restrict__ cmax) {
  __shared__ unsigned short Ah[128][40], Al[128][40], Bh[128][40], Bl[128][40];
  const int t = threadIdx.x;
  const int wave = t >> 6, lane = t & 63;
  const int wm = wave >> 1, wn = wave & 1;
  const int i0 = blockIdx.y * 128, j0 = blockIdx.x * 128;
  const int srow = t >> 1, shalf = t & 1;
  const size_t gAoff = (size_t)(i0 + srow) * ND + shalf * 16;
  const size_t gBoff = (size_t)(j0 + srow) * ND + shalf * 16;
  const int fr = lane & 15, fo = (lane >> 4) * 8;

  f32x4 acc[4][4];
  #pragma unroll
  for (int mi = 0; mi < 4; ++mi)
    #pragma unroll
    for (int ni = 0; ni < 4; ++ni) acc[mi][ni] = (f32x4){0.f, 0.f, 0.f, 0.f};

  for (int kc = 0; kc < ND; kc += 32) {
    bf16x8 a0 = *(const bf16x8*)(Xhi + gAoff + kc);
    bf16x8 a1 = *(const bf16x8*)(Xhi + gAoff + kc + 8);
    bf16x8 a2 = *(const bf16x8*)(Xlo + gAoff + kc);
    bf16x8 a3 = *(const bf16x8*)(Xlo + gAoff + kc + 8);
    bf16x8 b0 = *(const bf16x8*)(Xhi + gBoff + kc);
    bf16x8 b1 = *(const bf16x8*)(Xhi + gBoff + kc + 8);
    bf16x8 b2 = *(const bf16x8*)(Xlo + gBoff + kc);
    bf16x8 b3 = *(const bf16x8*)(Xlo + gBoff + kc + 8);
    *(bf16x8*)&Ah[srow][shalf * 16] = a0;
    *(bf16x8*)&Ah[srow][shalf * 16 + 8] = a1;
    *(bf16x8*)&Al[srow][shalf * 16] = a2;
    *(bf16x8*)&Al[srow][shalf * 16 + 8] = a3;
    *(bf16x8*)&Bh[srow][shalf * 16] = b0;
    *(bf16x8*)&Bh[srow][shalf * 16 + 8] = b1;
    *(bf16x8*)&Bl[srow][shalf * 16] = b2;
    *(bf16x8*)&Bl[srow][shalf * 16 + 8] = b3;
    __syncthreads();

    bf16x8 fah[4], fal[4], fbh[4], fbl[4];
    #pragma unroll
    for (int mi = 0; mi < 4; ++mi) {
      fah[mi] = *(const bf16x8*)&Ah[wm * 64 + mi * 16 + fr][fo];
      fal[mi] = *(const bf16x8*)&Al[wm * 64 + mi * 16 + fr][fo];
    }
    #pragma unroll
    for (int ni = 0; ni < 4; ++ni) {
      fbh[ni] = *(const bf16x8*)&Bh[wn * 64 + ni * 16 + fr][fo];
      fbl[ni] = *(const bf16x8*)&Bl[wn * 64 + ni * 16 + fr][fo];
    }
    #pragma unroll
    for (int mi = 0; mi < 4; ++mi)
      #pragma unroll
      for (int ni = 0; ni < 4; ++ni) {
        acc[mi][ni] = __builtin_amdgcn_mfma_f32_16x16x32_bf16(fah[mi], fbh[ni], acc[mi][ni], 0, 0, 0);
        acc[mi][ni] = __builtin_amdgcn_mfma_f32_16x16x32_bf16(fah[mi], fbl[ni], acc[mi][ni], 0, 0, 0);
        acc[mi][ni] = __builtin_amdgcn_mfma_f32_16x16x32_bf16(fal[mi], fbh[ni], acc[mi][ni], 0, 0, 0);
      }
    __syncthreads();
  }

  const int dr = (lane >> 4) * 4, dc = lane & 15;
  float njn[4];
  #pragma unroll
  for (int ni = 0; ni < 4; ++ni) njn[ni] = norms[j0 + wn * 64 + ni * 16 + dc];
  float lmax = 0.f;
  #pragma unroll
  for (int mi = 0; mi < 4; ++mi) {
    const int rbase = i0 + wm * 64 + mi * 16 + dr;
    float4 nin = *(const float4*)(norms + rbase);
    float nin4[4] = {nin.x, nin.y, nin.z, nin.w};
    #pragma unroll
    for (int ni = 0; ni < 4; ++ni) {
      const int cbase = j0 + wn * 64 + ni * 16 + dc;
      #pragma unroll
      for (int reg = 0; reg < 4; ++reg) {
        float v = 0.5f * fmaxf(nin4[reg] + njn[ni] - 2.f * acc[mi][ni][reg], 0.f);
        C[(size_t)(rbase + reg) * NB + cbase] = (_Float16)v;
        lmax = fmaxf(lmax, v);
      }
    }
  }
  lmax = wave_max(lmax);
  __shared__ float wmax[4];
  if (lane == 0) wmax[wave] = lmax;
  __syncthreads();
  if (t == 0) {
    float m = fmaxf(fmaxf(wmax[0], wmax[1]), fmaxf(wmax[2], wmax[3]));
    atomicMax(cmax, __float_as_uint(m));
  }
}

// ---- pass1: 4 rows per 1024-thread block; 256 threads/row; block max-then-sum ----
__global__ __launch_bounds__(1024) void k_pass1(
    const _Float16* __restrict__ C, const float* __restrict__ gpot,
    const float* __restrict__ fxx_in, const float* __restrict__ fyy_in,
    float* __restrict__ f_out, float* __restrict__ fxx_out, float* __restrict__ fyy_out,
    const int* __restrict__ pgroup, const int* __restrict__ starts,
    const float* __restrict__ lc2, const unsigned int* __restrict__ cmax, int iter) {
  const int t = threadIdx.x;
  const int q = t >> 8, tq = t & 255;      // row-quarter, tid within quarter
  const int lane = t & 63, wq = (t >> 6) & 3;
  const int i = blockIdx.x * 4 + q;
  const float fyi_i = fyy_in[i];
  const float fxi_i = fxx_in[i];
  const float eps = eps_at(cmax, iter);
  const float inv2 = LOG2E / eps;
  const float ninv2 = -inv2;
  const int gi = pgroup[i];
  const float lb2 = -11.0f;  // -log2(2048)
  const _Float16* Crow = C + (size_t)i * NB;
  const float* gr = gpot + (size_t)gi * NB;

  // 8 columns per thread
  const int j0 = tq * 8;
  h8 ch = *(const h8*)(Crow + j0);
  float4 g0 = *(const float4*)(gr + j0);
  float4 g1 = *(const float4*)(gr + j0 + 4);
  float4 y0 = *(const float4*)(fyy_in + j0);
  float4 y1 = *(const float4*)(fyy_in + j0 + 4);
  float gv[8] = {g0.x, g0.y, g0.z, g0.w, g1.x, g1.y, g1.z, g1.w};
  float yv[8] = {y0.x, y0.y, y0.z, y0.w, y1.x, y1.y, y1.z, y1.w};
  float tA[8], tY[8];
  #pragma unroll
  for (int e = 0; e < 8; ++e) {
    float ci = fmaf((float)ch[e], ninv2, lb2);
    tA[e] = fmaf(gv[e], inv2, ci);
    tY[e] = fmaf(yv[e], inv2, ci);
  }
  float lmA = fmaxf(fmaxf(fmaxf(tA[0], tA[1]), fmaxf(tA[2], tA[3])),
                    fmaxf(fmaxf(tA[4], tA[5]), fmaxf(tA[6], tA[7])));
  float lmY = fmaxf(fmaxf(fmaxf(tY[0], tY[1]), fmaxf(tY[2], tY[3])),
                    fmaxf(fmaxf(tY[4], tY[5]), fmaxf(tY[6], tY[7])));

  // fxx: own segment, 1 col per thread (stride 256)
  const float lcg = lc2[gi];
  const int seg0 = starts[gi], seg1 = starts[gi + 1];
  float mXl = NEGINF, sXl = 0.f;
  for (int j = seg0 + tq; j < seg1; j += 256)
    online1(mXl, sXl, fmaf(fxx_in[j], inv2, lcg) + (float)Crow[j] * ninv2);

  // block max reduce (3 channels per row-quarter, one LDS round-trip)
  __shared__ float rA[4][4], rB[4][4], rC[4][4], rA2[4][4], rB2[4][4], rC2[4][4];
  float wmA = wave_max(lmA), wmY = wave_max(lmY), wmX = wave_max(mXl);
  if (lane == 0) { rA[q][wq] = wmA; rB[q][wq] = wmY; rC[q][wq] = wmX; }
  __syncthreads();
  const float mA = fmaxf(fmaxf(rA[q][0], rA[q][1]), fmaxf(rA[q][2], rA[q][3]));
  const float mY = fmaxf(fmaxf(rB[q][0], rB[q][1]), fmaxf(rB[q][2], rB[q][3]));
  const float mX = fmaxf(fmaxf(rC[q][0], rC[q][1]), fmaxf(rC[q][2], rC[q][3]));

  // independent exp2 sums with block max
  float sA = 0.f, sY = 0.f;
  #pragma unroll
  for (int e = 0; e < 8; ++e) {
    sA += fexp2(tA[e] - mA);
    sY += fexp2(tY[e] - mY);
  }
  float sX = (mXl == NEGINF) ? 0.f : sXl * fexp2(mXl - mX);
  float wsA = wave_sum(sA), wsY = wave_sum(sY), wsX = wave_sum(sX);
  if (lane == 0) { rA2[q][wq] = wsA; rB2[q][wq] = wsY; rC2[q][wq] = wsX; }
  __syncthreads();
  if (tq == 0) {
    const float SA = (rA2[q][0] + rA2[q][1]) + (rA2[q][2] + rA2[q][3]);
    const float SY = (rB2[q][0] + rB2[q][1]) + (rB2[q][2] + rB2[q][3]);
    const float SX = (rC2[q][0] + rC2[q][1]) + (rC2[q][2] + rC2[q][3]);
    f_out[i]   = -eps * ((mA + flog2(SA)) * LN2);
    fyy_out[i] = 0.5f * (fyi_i - eps * ((mY + flog2(SY)) * LN2));
    fxx_out[i] = 0.5f * (fxi_i - eps * ((mX + flog2(SX)) * LN2));
  }
}

// ---- pass2: 4 rows per 1024-thread block; per row 8 groups x 32 lanes ----
__global__ __launch_bounds__(1024) void k_pass2(
    const _Float16* __restrict__ C, const float* __restrict__ f,
    float* __restrict__ gpot, const int* __restrict__ starts,
    const float* __restrict__ lc2, const unsigned int* __restrict__ cmax, int iter) {
  const int t = threadIdx.x;
  const int q = t >> 8, tq = t & 255;
  const int i = blockIdx.x * 4 + q;
  const float eps = eps_at(cmax, iter);
  const float inv2 = LOG2E / eps;
  const float ninv2 = -inv2;
  const _Float16* Crow = C + (size_t)i * NB;
  const int gl = tq >> 5, li = tq & 31;
  const float lcg = lc2[gl];
  const int seg0 = starts[gl], seg1 = starts[gl + 1];
  const int a0 = (seg0 + 7) & ~7;   // aligned vector start
  const int a1 = seg1 & ~7;          // aligned vector end

  // vector body: lane li covers 8 contiguous cols per k-step
  float tv[16];
  #pragma unroll
  for (int k = 0; k < 16; ++k) tv[k] = NEGINF;
  #pragma unroll
  for (int k = 0; k < 2; ++k) {
    const int j = a0 + (li + k * 32) * 8;
    if (j + 8 <= a1) {
      h8 ch = *(const h8*)(Crow + j);
      float4 f0 = *(const float4*)(f + j);
      float4 f1 = *(const float4*)(f + j + 4);
      float fv[8] = {f0.x, f0.y, f0.z, f0.w, f1.x, f1.y, f1.z, f1.w};
      #pragma unroll
      for (int e = 0; e < 8; ++e)
        tv[k * 8 + e] = fmaf(fv[e], inv2, lcg) + (float)ch[e] * ninv2;
    }
  }
  // head (< a0) and tail (>= a1) scalars, <=7 each
  float th = NEGINF, tt = NEGINF;
  {
    const int jh = seg0 + li;
    if (jh < a0 && jh < seg1)
      th = fmaf(f[jh], inv2, lcg) + (float)Crow[jh] * ninv2;
    const int jt = a1 + li;
    if (jt >= a0 && jt < seg1)
      tt = fmaf(f[jt], inv2, lcg) + (float)Crow[jt] * ninv2;
  }
  float m0 = fmaxf(fmaxf(tv[0], tv[1]), fmaxf(tv[2], tv[3]));
  float m1 = fmaxf(fmaxf(tv[4], tv[5]), fmaxf(tv[6], tv[7]));
  float m2 = fmaxf(fmaxf(tv[8], tv[9]), fmaxf(tv[10], tv[11]));
  float m3 = fmaxf(fmaxf(tv[12], tv[13]), fmaxf(tv[14], tv[15]));
  float m = fmaxf(fmaxf(fmaxf(m0, m1), fmaxf(m2, m3)), fmaxf(th, tt));
  float s = 0.f;
  if (m != NEGINF) {
    float s0 = 0.f, s1 = 0.f, s2 = 0.f, s3 = 0.f;
    #pragma unroll
    for (int k = 0; k < 16; k += 4) {
      s0 += fexp2(tv[k] - m); s1 += fexp2(tv[k + 1] - m);
      s2 += fexp2(tv[k + 2] - m); s3 += fexp2(tv[k + 3] - m);
    }
    s = ((s0 + s1) + (s2 + s3)) + (fexp2(th - m) + fexp2(tt - m));
  }
  // cleanup for pathological segments (> ~512 cols): normally zero iterations
  {
    float mc = NEGINF, sc = 0.f;
    for (int j = a0 + 512 + li; j < a1; j += 32)
      online1(mc, sc, fmaf(f[j], inv2, lcg) + (float)Crow[j] * ninv2);
    if (mc != NEGINF) {
      float M = fmaxf(m, mc);
      float sn = ((m == NEGINF) ? 0.f : s * fexp2(m - M)) + sc * fexp2(mc - M);
      m = M; s = sn;
    }
  }
  // 32-lane LSE reduce
  float M = m;
  #pragma unroll
  for (int o = 16; o; o >>= 1) M = fmaxf(M, __shfl_xor(M, o, 32));
  float sv = (m == NEGINF) ? 0.f : s * fexp2(m - M);
  #pragma unroll
  for (int o = 16; o; o >>= 1) sv += __shfl_xor(sv, o, 32);
  if (li == 0) {
    float r = (M == NEGINF) ? 0.f : -eps * ((M + flog2(sv)) * LN2);
    gpot[(size_t)gl * NB + i] = r;
  }
}

// ---- finalize: 25 reductions, wave-parallel ----
__global__ __launch_bounds__(256) void k_final(
    const float* __restrict__ f, const float* __restrict__ gpot,
    const float* __restrict__ fxx, const float* __restrict__ fyy,
    const int* __restrict__ counts, const int* __restrict__ starts,
    float* __restrict__ out) {
  __shared__ float results[25];
  const int t = threadIdx.x, lane = t & 63, wid = t >> 6;
  for (int q = wid; q < 25; q += 4) {
    float v = 0.f;
    if (q < 8) {
      for (int i = starts[q] + lane; i < starts[q + 1]; i += 64) v += f[i];
    } else if (q < 16) {
      const int g = q - 8;
      for (int i = starts[g] + lane; i < starts[g + 1]; i += 64) v += fxx[i];
    } else if (q < 24) {
      const float* gp = gpot + (size_t)(q - 16) * NB;
      for (int i = lane; i < NB; i += 64) v += gp[i];
    } else {
      for (int i = lane; i < NB; i += 64) v += fyy[i];
    }
    v = wave_sum(v);
    if (lane == 0) results[q] = v;
  }
  __syncthreads();
  if (t == 0) {
    const float syy = results[24] / (float)NB;
    float tot = 0.f; int nv = 0;
    float sg[8];
    for (int g = 0; g < NG; ++g) {
      float cnt = (float)(counts[g] < 1 ? 1 : counts[g]);
      float S = (results[g] - results[8 + g]) / cnt + results[16 + g] / (float)NB - syy;
      int valid = counts[g] >= 2 ? 1 : 0;
      float sv = valid ? S : 0.f;
      sg[g] = sv;
      if (valid) { tot += sv; nv++; }
    }
    tot /= (float)(nv < 1 ? 1 : nv);
    out[0] = tot;
    for (int g = 0; g < NG; ++g) out[1 + g] = sg[g];
  }
}

extern "C" void kernel_launch(void* const* d_in, const int* in_sizes, int n_in,
                              void* d_out, int out_size, void* d_ws, size_t ws_size,
                              hipStream_t stream) {
  (void)in_sizes; (void)n_in; (void)out_size; (void)ws_size;
  const float* X = (const float*)d_in[0];
  const int* sub = (const int*)d_in[1];

  char* w = (char*)d_ws;
  size_t off = 0;
  auto alloc = [&](size_t bytes) -> void* {
    void* p = w + off;
    off = (off + bytes + 255) & ~(size_t)255;
    return p;
  };
  _Float16* C         = (_Float16*)alloc((size_t)NB * NB * 2);
  unsigned short* Xhi = (unsigned short*)alloc((size_t)NB * ND * 2);
  unsigned short* Xlo = (unsigned short*)alloc((size_t)NB * ND * 2);
  float* norms  = (float*)alloc(NB * 4);
  int*   order  = (int*)alloc(NB * 4);
  int*   pgroup = (int*)alloc(NB * 4);
  float* f      = (float*)alloc(NB * 4);
  float* gpot   = (float*)alloc((size_t)NG * NB * 4);
  float* fxx0   = (float*)alloc(NB * 4);
  float* fxx1   = (float*)alloc(NB * 4);
  float* fyy0   = (float*)alloc(NB * 4);
  float* fyy1   = (float*)alloc(NB * 4);
  int*   counts = (int*)alloc(NG * 4);
  int*   starts = (int*)alloc((NG + 1) * 4);
  float* lc2    = (float*)alloc(NG * 4);
  unsigned int* cmax = (unsigned int*)alloc(4);

  k_setup<<<1, 256, 0, stream>>>(sub, order, pgroup, counts, starts, lc2, cmax,
                                 gpot, f, fxx0, fyy0);
  k_permute<<<NB, 128, 0, stream>>>(X, order, Xhi, Xlo, norms);
  k_gemm<<<dim3(16, 16), 256, 0, stream>>>(Xhi, Xlo, norms, C, cmax);
  for (int it = 0; it < NITER; ++it) {
    float* fxi = (it & 1) ? fxx1 : fxx0;
    float* fxo = (it & 1) ? fxx0 : fxx1;
    float* fyi = (it & 1) ? fyy1 : fyy0;
    float* fyo = (it & 1) ? fyy0 : fyy1;
    k_pass1<<<NB / 4, 1024, 0, stream>>>(C, gpot, fxi, fyi, f, fxo, fyo,
                                         pgroup, starts, lc2, cmax, it);
    k_pass2<<<NB / 4, 1024, 0, stream>>>(C, f, gpot, starts, lc2, cmax, it);
  }
  // after it=63 (odd), outputs landed in fxx0 / fyy0
  k_final<<<1, 256, 0, stream>>>(f, gpot, fxx0, fyy0, counts, starts, (float*)d_out);
}

// Round 8
// 862.167 us; speedup vs baseline: 1.0565x; 1.0565x over previous
//
#include <hip/hip_runtime.h>
#include <math.h>

#define NB 2048
#define ND 512
#define NG 8
#define NITER 64

typedef _Float16 h8 __attribute__((ext_vector_type(8)));
typedef short bf16x8 __attribute__((ext_vector_type(8)));
typedef short us4 __attribute__((ext_vector_type(4)));
typedef float f32x4 __attribute__((ext_vector_type(4)));

#define LOG2E 1.4426950408889634f
#define LN2   0.6931471805599453f
#define NEGINF (-__builtin_inff())
#define L2_09 -0.15200309344504997f  /* log2(0.9) */

__device__ __forceinline__ float fexp2(float x) { return __builtin_amdgcn_exp2f(x); }
__device__ __forceinline__ float flog2(float x) { return __builtin_amdgcn_logf(x); }

__device__ __forceinline__ unsigned short f2bf(float x) {
  unsigned u = __float_as_uint(x);
  unsigned r = u + 0x7fff + ((u >> 16) & 1);
  return (unsigned short)(r >> 16);
}
__device__ __forceinline__ float bf2f(unsigned short h) {
  return __uint_as_float(((unsigned)h) << 16);
}

__device__ __forceinline__ void online1(float& m, float& s, float t) {
  float M = fmaxf(m, t);
  s = fmaf(s, fexp2(m - M), fexp2(t - M));
  m = M;
}
__device__ __forceinline__ float wave_max(float v) {
  #pragma unroll
  for (int o = 32; o; o >>= 1) v = fmaxf(v, __shfl_xor(v, o));
  return v;
}
__device__ __forceinline__ float wave_sum(float v) {
  #pragma unroll
  for (int o = 32; o; o >>= 1) v += __shfl_xor(v, o);
  return v;
}

// ---- inline eps schedule ----
__device__ __forceinline__ float eps_at(const unsigned int* cmax, int t) {
  float cm = __uint_as_float(*cmax);
  float diam = sqrtf(2.f * fmaxf(cm, 1e-12f));
  float sig = fmaxf(diam * fexp2((float)t * L2_09), 0.05f);
  return sig * sig;
}

// ---- setup: O(N) stable counting sort via packed 16-bit scan ----
__global__ __launch_bounds__(256) void k_setup(
    const int* __restrict__ sub_raw,
    int* __restrict__ order, int* __restrict__ pgroup,
    int* __restrict__ counts, int* __restrict__ starts,
    float* __restrict__ lc2, unsigned int* __restrict__ cmax,
    _Float16* __restrict__ gpot, _Float16* __restrict__ f,
    _Float16* __restrict__ fxx0, _Float16* __restrict__ fyy0) {
  __shared__ int subs[NB];
  __shared__ unsigned long long scanLo[256], scanHi[256];
  __shared__ int st[NG + 1];
  __shared__ int odd_nz;
  const int t = threadIdx.x;
  if (t == 0) odd_nz = 0;
  __syncthreads();
  int nz = 0;
  for (int k = t; k < 1024; k += 256) nz |= (sub_raw[2 * k + 1] != 0) ? 1 : 0;
  if (nz) atomicOr(&odd_nz, 1);
  __syncthreads();
  const int stride = odd_nz ? 1 : 2;
  for (int i = t; i < NB; i += 256) subs[i] = sub_raw[(size_t)i * stride] & 7;
  __syncthreads();
  unsigned long long cLo = 0ull, cHi = 0ull;
  #pragma unroll
  for (int k = 0; k < 8; ++k) {
    int g = subs[8 * t + k];
    unsigned long long inc = 1ull << ((g & 3) * 16);
    if (g < 4) cLo += inc; else cHi += inc;
  }
  scanLo[t] = cLo; scanHi[t] = cHi;
  __syncthreads();
  for (int s = 1; s < 256; s <<= 1) {
    unsigned long long aLo = (t >= s) ? scanLo[t - s] : 0ull;
    unsigned long long aHi = (t >= s) ? scanHi[t - s] : 0ull;
    __syncthreads();
    scanLo[t] += aLo; scanHi[t] += aHi;
    __syncthreads();
  }
  if (t == 0) {
    unsigned long long TLo = scanLo[255], THi = scanHi[255];
    int a = 0;
    for (int g = 0; g < NG; ++g) {
      st[g] = a;
      a += (int)(((g < 4 ? TLo : THi) >> ((g & 3) * 16)) & 0xffffull);
    }
    st[NG] = a;
  }
  __syncthreads();
  unsigned long long bLo = t ? scanLo[t - 1] : 0ull;
  unsigned long long bHi = t ? scanHi[t - 1] : 0ull;
  #pragma unroll
  for (int k = 0; k < 8; ++k) {
    int idx = 8 * t + k;
    int g = subs[idx];
    int sh = (g & 3) * 16;
    unsigned long long cur = (g < 4) ? bLo : bHi;
    int r = (int)((cur >> sh) & 0xffffull);
    int pos = st[g] + r;
    order[pos] = idx;
    pgroup[pos] = g;
    if (g < 4) bLo += 1ull << sh; else bHi += 1ull << sh;
  }
  if (t < NG) {
    int c = st[t + 1] - st[t];
    counts[t] = c;
    int cc = c < 1 ? 1 : c;
    lc2[t] = -flog2((float)cc);
  }
  if (t < NG + 1) starts[t] = st[t];
  if (t == 0) *cmax = 0u;
  {
    int* g4 = (int*)gpot;             // NG*NB fp16 = NG*NB/2 ints
    for (int i = t; i < NG * NB / 2; i += 256) g4[i] = 0;
    int* fz = (int*)f;
    int* xz = (int*)fxx0;
    int* yz = (int*)fyy0;
    for (int i = t; i < NB / 2; i += 256) { fz[i] = 0; xz[i] = 0; yz[i] = 0; }
  }
}

// ---- permute + split into bf16 hi/lo + row norms (norms from exact f32) ----
__global__ __launch_bounds__(128) void k_permute(
    const float* __restrict__ X, const int* __restrict__ order,
    unsigned short* __restrict__ Xhi, unsigned short* __restrict__ Xlo,
    float* __restrict__ norms) {
  const int i = blockIdx.x, t = threadIdx.x;
  const int src = order[i];
  float4 v = ((const float4*)(X + (size_t)src * ND))[t];
  float vv[4] = {v.x, v.y, v.z, v.w};
  unsigned short h[4], l[4];
  #pragma unroll
  for (int e = 0; e < 4; ++e) {
    h[e] = f2bf(vv[e]);
    l[e] = f2bf(vv[e] - bf2f(h[e]));
  }
  us4 hv = { (short)h[0], (short)h[1], (short)h[2], (short)h[3] };
  us4 lv = { (short)l[0], (short)l[1], (short)l[2], (short)l[3] };
  *(us4*)(Xhi + (size_t)i * ND + t * 4) = hv;
  *(us4*)(Xlo + (size_t)i * ND + t * 4) = lv;
  float ss = v.x * v.x + v.y * v.y + v.z * v.z + v.w * v.w;
  #pragma unroll
  for (int o = 32; o; o >>= 1) ss += __shfl_xor(ss, o);
  __shared__ float p[2];
  if ((t & 63) == 0) p[t >> 6] = ss;
  __syncthreads();
  if (t == 0) norms[i] = p[0] + p[1];
}

// ---- C = fp16(0.5*relu(n_i + n_j - 2 X X^T)) via split-bf16 MFMA + global max ----
__global__ __launch_bounds__(256, 1) void k_gemm(
    const unsigned short* __restrict__ Xhi, const unsigned short* __restrict__ Xlo,
    const float* __restrict__ norms, _Float16* __restrict__ C,
    unsigned int* __restrict__ cmax) {
  __shared__ unsigned short Ah[128][40], Al[128][40], Bh[128][40], Bl[128][40];
  const int t = threadIdx.x;
  const int wave = t >> 6, lane = t & 63;
  const int wm = wave >> 1, wn = wave & 1;
  const int i0 = blockIdx.y * 128, j0 = blockIdx.x * 128;
  const int srow = t >> 1, shalf = t & 1;
  const size_t gAoff = (size_t)(i0 + srow) * ND + shalf * 16;
  const size_t gBoff = (size_t)(j0 + srow) * ND + shalf * 16;
  const int fr = lane & 15, fo = (lane >> 4) * 8;

  f32x4 acc[4][4];
  #pragma unroll
  for (int mi = 0; mi < 4; ++mi)
    #pragma unroll
    for (int ni = 0; ni < 4; ++ni) acc[mi][ni] = (f32x4){0.f, 0.f, 0.f, 0.f};

  for (int kc = 0; kc < ND; kc += 32) {
    bf16x8 a0 = *(const bf16x8*)(Xhi + gAoff + kc);
    bf16x8 a1 = *(const bf16x8*)(Xhi + gAoff + kc + 8);
    bf16x8 a2 = *(const bf16x8*)(Xlo + gAoff + kc);
    bf16x8 a3 = *(const bf16x8*)(Xlo + gAoff + kc + 8);
    bf16x8 b0 = *(const bf16x8*)(Xhi + gBoff + kc);
    bf16x8 b1 = *(const bf16x8*)(Xhi + gBoff + kc + 8);
    bf16x8 b2 = *(const bf16x8*)(Xlo + gBoff + kc);
    bf16x8 b3 = *(const bf16x8*)(Xlo + gBoff + kc + 8);
    *(bf16x8*)&Ah[srow][shalf * 16] = a0;
    *(bf16x8*)&Ah[srow][shalf * 16 + 8] = a1;
    *(bf16x8*)&Al[srow][shalf * 16] = a2;
    *(bf16x8*)&Al[srow][shalf * 16 + 8] = a3;
    *(bf16x8*)&Bh[srow][shalf * 16] = b0;
    *(bf16x8*)&Bh[srow][shalf * 16 + 8] = b1;
    *(bf16x8*)&Bl[srow][shalf * 16] = b2;
    *(bf16x8*)&Bl[srow][shalf * 16 + 8] = b3;
    __syncthreads();

    bf16x8 fah[4], fal[4], fbh[4], fbl[4];
    #pragma unroll
    for (int mi = 0; mi < 4; ++mi) {
      fah[mi] = *(const bf16x8*)&Ah[wm * 64 + mi * 16 + fr][fo];
      fal[mi] = *(const bf16x8*)&Al[wm * 64 + mi * 16 + fr][fo];
    }
    #pragma unroll
    for (int ni = 0; ni < 4; ++ni) {
      fbh[ni] = *(const bf16x8*)&Bh[wn * 64 + ni * 16 + fr][fo];
      fbl[ni] = *(const bf16x8*)&Bl[wn * 64 + ni * 16 + fr][fo];
    }
    #pragma unroll
    for (int mi = 0; mi < 4; ++mi)
      #pragma unroll
      for (int ni = 0; ni < 4; ++ni) {
        acc[mi][ni] = __builtin_amdgcn_mfma_f32_16x16x32_bf16(fah[mi], fbh[ni], acc[mi][ni], 0, 0, 0);
        acc[mi][ni] = __builtin_amdgcn_mfma_f32_16x16x32_bf16(fah[mi], fbl[ni], acc[mi][ni], 0, 0, 0);
        acc[mi][ni] = __builtin_amdgcn_mfma_f32_16x16x32_bf16(fal[mi], fbh[ni], acc[mi][ni], 0, 0, 0);
      }
    __syncthreads();
  }

  const int dr = (lane >> 4) * 4, dc = lane & 15;
  float njn[4];
  #pragma unroll
  for (int ni = 0; ni < 4; ++ni) njn[ni] = norms[j0 + wn * 64 + ni * 16 + dc];
  float lmax = 0.f;
  #pragma unroll
  for (int mi = 0; mi < 4; ++mi) {
    const int rbase = i0 + wm * 64 + mi * 16 + dr;
    float4 nin = *(const float4*)(norms + rbase);
    float nin4[4] = {nin.x, nin.y, nin.z, nin.w};
    #pragma unroll
    for (int ni = 0; ni < 4; ++ni) {
      const int cbase = j0 + wn * 64 + ni * 16 + dc;
      #pragma unroll
      for (int reg = 0; reg < 4; ++reg) {
        float v = 0.5f * fmaxf(nin4[reg] + njn[ni] - 2.f * acc[mi][ni][reg], 0.f);
        C[(size_t)(rbase + reg) * NB + cbase] = (_Float16)v;
        lmax = fmaxf(lmax, v);
      }
    }
  }
  lmax = wave_max(lmax);
  __shared__ float wmax[4];
  if (lane == 0) wmax[wave] = lmax;
  __syncthreads();
  if (t == 0) {
    float m = fmaxf(fmaxf(wmax[0], wmax[1]), fmaxf(wmax[2], wmax[3]));
    atomicMax(cmax, __float_as_uint(m));
  }
}

// ---- pass1: one BLOCK per row; 256 threads x 8 cols; block max-then-sum ----
__global__ __launch_bounds__(256) void k_pass1(
    const _Float16* __restrict__ C, const _Float16* __restrict__ gpot,
    const _Float16* __restrict__ fxx_in, const _Float16* __restrict__ fyy_in,
    _Float16* __restrict__ f_out, _Float16* __restrict__ fxx_out, _Float16* __restrict__ fyy_out,
    const int* __restrict__ pgroup, const int* __restrict__ starts,
    const float* __restrict__ lc2, const unsigned int* __restrict__ cmax, int iter) {
  const int i = blockIdx.x;
  const int t = threadIdx.x, lane = t & 63, wid = t >> 6;
  const float fyi_i = (float)fyy_in[i];
  const float fxi_i = (float)fxx_in[i];
  const float eps = eps_at(cmax, iter);
  const float inv2 = LOG2E / eps;
  const float ninv2 = -inv2;
  const int gi = pgroup[i];
  const float lb2 = -11.0f;  // -log2(2048)
  const _Float16* Crow = C + (size_t)i * NB;
  const _Float16* gr = gpot + (size_t)gi * NB;

  // 8 columns per thread
  const int j0 = t * 8;
  h8 ch = *(const h8*)(Crow + j0);
  h8 gh = *(const h8*)(gr + j0);
  h8 yh = *(const h8*)(fyy_in + j0);
  float tA[8], tY[8];
  #pragma unroll
  for (int e = 0; e < 8; ++e) {
    float ci = fmaf((float)ch[e], ninv2, lb2);
    tA[e] = fmaf((float)gh[e], inv2, ci);
    tY[e] = fmaf((float)yh[e], inv2, ci);
  }
  float lmA = fmaxf(fmaxf(fmaxf(tA[0], tA[1]), fmaxf(tA[2], tA[3])),
                    fmaxf(fmaxf(tA[4], tA[5]), fmaxf(tA[6], tA[7])));
  float lmY = fmaxf(fmaxf(fmaxf(tY[0], tY[1]), fmaxf(tY[2], tY[3])),
                    fmaxf(fmaxf(tY[4], tY[5]), fmaxf(tY[6], tY[7])));

  // fxx: own segment, 1 col per thread (stride 256)
  const float lcg = lc2[gi];
  const int seg0 = starts[gi], seg1 = starts[gi + 1];
  float mXl = NEGINF, sXl = 0.f;
  for (int j = seg0 + t; j < seg1; j += 256)
    online1(mXl, sXl, fmaf((float)fxx_in[j], inv2, lcg) + (float)Crow[j] * ninv2);

  // block max reduce (3 channels, one LDS round-trip)
  __shared__ float rA[4], rB[4], rC[4], rA2[4], rB2[4], rC2[4];
  float wmA = wave_max(lmA), wmY = wave_max(lmY), wmX = wave_max(mXl);
  if (lane == 0) { rA[wid] = wmA; rB[wid] = wmY; rC[wid] = wmX; }
  __syncthreads();
  const float mA = fmaxf(fmaxf(rA[0], rA[1]), fmaxf(rA[2], rA[3]));
  const float mY = fmaxf(fmaxf(rB[0], rB[1]), fmaxf(rB[2], rB[3]));
  const float mX = fmaxf(fmaxf(rC[0], rC[1]), fmaxf(rC[2], rC[3]));

  // independent exp2 sums with block max
  float sA = 0.f, sY = 0.f;
  #pragma unroll
  for (int e = 0; e < 8; ++e) {
    sA += fexp2(tA[e] - mA);
    sY += fexp2(tY[e] - mY);
  }
  float sX = (mXl == NEGINF) ? 0.f : sXl * fexp2(mXl - mX);
  float wsA = wave_sum(sA), wsY = wave_sum(sY), wsX = wave_sum(sX);
  if (lane == 0) { rA2[wid] = wsA; rB2[wid] = wsY; rC2[wid] = wsX; }
  __syncthreads();
  if (t == 0) {
    const float SA = (rA2[0] + rA2[1]) + (rA2[2] + rA2[3]);
    const float SY = (rB2[0] + rB2[1]) + (rB2[2] + rB2[3]);
    const float SX = (rC2[0] + rC2[1]) + (rC2[2] + rC2[3]);
    f_out[i]   = (_Float16)(-eps * ((mA + flog2(SA)) * LN2));
    fyy_out[i] = (_Float16)(0.5f * (fyi_i - eps * ((mY + flog2(SY)) * LN2)));
    fxx_out[i] = (_Float16)(0.5f * (fxi_i - eps * ((mX + flog2(SX)) * LN2)));
  }
}

// ---- pass2: one BLOCK per row; 8 groups x 32 lanes; vectorized segment loads ----
__global__ __launch_bounds__(256) void k_pass2(
    const _Float16* __restrict__ C, const _Float16* __restrict__ f,
    _Float16* __restrict__ gpot, const int* __restrict__ starts,
    const float* __restrict__ lc2, const unsigned int* __restrict__ cmax, int iter) {
  const int i = blockIdx.x;
  const int t = threadIdx.x;
  const float eps = eps_at(cmax, iter);
  const float inv2 = LOG2E / eps;
  const float ninv2 = -inv2;
  const _Float16* Crow = C + (size_t)i * NB;
  const int gl = t >> 5, li = t & 31;
  const float lcg = lc2[gl];
  const int seg0 = starts[gl], seg1 = starts[gl + 1];
  const int a0 = (seg0 + 7) & ~7;   // aligned vector start
  const int a1 = seg1 & ~7;          // aligned vector end

  // vector body: lane li covers 8 contiguous cols per k-step
  float tv[16];
  #pragma unroll
  for (int k = 0; k < 16; ++k) tv[k] = NEGINF;
  #pragma unroll
  for (int k = 0; k < 2; ++k) {
    const int j = a0 + (li + k * 32) * 8;
    if (j + 8 <= a1) {
      h8 ch = *(const h8*)(Crow + j);
      h8 fh = *(const h8*)(f + j);
      #pragma unroll
      for (int e = 0; e < 8; ++e)
        tv[k * 8 + e] = fmaf((float)fh[e], inv2, lcg) + (float)ch[e] * ninv2;
    }
  }
  // head (< a0) and tail (>= a1) scalars, <=7 each
  float th = NEGINF, tt = NEGINF;
  {
    const int jh = seg0 + li;
    if (jh < a0 && jh < seg1)
      th = fmaf((float)f[jh], inv2, lcg) + (float)Crow[jh] * ninv2;
    const int jt = a1 + li;
    if (jt >= a0 && jt < seg1)
      tt = fmaf((float)f[jt], inv2, lcg) + (float)Crow[jt] * ninv2;
  }
  float m0 = fmaxf(fmaxf(tv[0], tv[1]), fmaxf(tv[2], tv[3]));
  float m1 = fmaxf(fmaxf(tv[4], tv[5]), fmaxf(tv[6], tv[7]));
  float m2 = fmaxf(fmaxf(tv[8], tv[9]), fmaxf(tv[10], tv[11]));
  float m3 = fmaxf(fmaxf(tv[12], tv[13]), fmaxf(tv[14], tv[15]));
  float m = fmaxf(fmaxf(fmaxf(m0, m1), fmaxf(m2, m3)), fmaxf(th, tt));
  float s = 0.f;
  if (m != NEGINF) {
    float s0 = 0.f, s1 = 0.f, s2 = 0.f, s3 = 0.f;
    #pragma unroll
    for (int k = 0; k < 16; k += 4) {
      s0 += fexp2(tv[k] - m); s1 += fexp2(tv[k + 1] - m);
      s2 += fexp2(tv[k + 2] - m); s3 += fexp2(tv[k + 3] - m);
    }
    s = ((s0 + s1) + (s2 + s3)) + (fexp2(th - m) + fexp2(tt - m));
  }
  // cleanup for pathological segments (> ~512 cols): normally zero iterations
  {
    float mc = NEGINF, sc = 0.f;
    for (int j = a0 + 512 + li; j < a1; j += 32)
      online1(mc, sc, fmaf((float)f[j], inv2, lcg) + (float)Crow[j] * ninv2);
    if (mc != NEGINF) {
      float M = fmaxf(m, mc);
      float sn = ((m == NEGINF) ? 0.f : s * fexp2(m - M)) + sc * fexp2(mc - M);
      m = M; s = sn;
    }
  }
  // 32-lane LSE reduce
  float M = m;
  #pragma unroll
  for (int o = 16; o; o >>= 1) M = fmaxf(M, __shfl_xor(M, o, 32));
  float sv = (m == NEGINF) ? 0.f : s * fexp2(m - M);
  #pragma unroll
  for (int o = 16; o; o >>= 1) sv += __shfl_xor(sv, o, 32);
  if (li == 0) {
    float r = (M == NEGINF) ? 0.f : -eps * ((M + flog2(sv)) * LN2);
    gpot[(size_t)gl * NB + i] = (_Float16)r;
  }
}

// ---- finalize: 25 reductions, wave-parallel ----
__global__ __launch_bounds__(256) void k_final(
    const _Float16* __restrict__ f, const _Float16* __restrict__ gpot,
    const _Float16* __restrict__ fxx, const _Float16* __restrict__ fyy,
    const int* __restrict__ counts, const int* __restrict__ starts,
    float* __restrict__ out) {
  __shared__ float results[25];
  const int t = threadIdx.x, lane = t & 63, wid = t >> 6;
  for (int q = wid; q < 25; q += 4) {
    float v = 0.f;
    if (q < 8) {
      for (int i = starts[q] + lane; i < starts[q + 1]; i += 64) v += (float)f[i];
    } else if (q < 16) {
      const int g = q - 8;
      for (int i = starts[g] + lane; i < starts[g + 1]; i += 64) v += (float)fxx[i];
    } else if (q < 24) {
      const _Float16* gp = gpot + (size_t)(q - 16) * NB;
      for (int i = lane; i < NB; i += 64) v += (float)gp[i];
    } else {
      for (int i = lane; i < NB; i += 64) v += (float)fyy[i];
    }
    v = wave_sum(v);
    if (lane == 0) results[q] = v;
  }
  __syncthreads();
  if (t == 0) {
    const float syy = results[24] / (float)NB;
    float tot = 0.f; int nv = 0;
    float sg[8];
    for (int g = 0; g < NG; ++g) {
      float cnt = (float)(counts[g] < 1 ? 1 : counts[g]);
      float S = (results[g] - results[8 + g]) / cnt + results[16 + g] / (float)NB - syy;
      int valid = counts[g] >= 2 ? 1 : 0;
      float sv = valid ? S : 0.f;
      sg[g] = sv;
      if (valid) { tot += sv; nv++; }
    }
    tot /= (float)(nv < 1 ? 1 : nv);
    out[0] = tot;
    for (int g = 0; g < NG; ++g) out[1 + g] = sg[g];
  }
}

extern "C" void kernel_launch(void* const* d_in, const int* in_sizes, int n_in,
                              void* d_out, int out_size, void* d_ws, size_t ws_size,
                              hipStream_t stream) {
  (void)in_sizes; (void)n_in; (void)out_size; (void)ws_size;
  const float* X = (const float*)d_in[0];
  const int* sub = (const int*)d_in[1];

  char* w = (char*)d_ws;
  size_t off = 0;
  auto alloc = [&](size_t bytes) -> void* {
    void* p = w + off;
    off = (off + bytes + 255) & ~(size_t)255;
    return p;
  };
  _Float16* C         = (_Float16*)alloc((size_t)NB * NB * 2);
  unsigned short* Xhi = (unsigned short*)alloc((size_t)NB * ND * 2);
  unsigned short* Xlo = (unsigned short*)alloc((size_t)NB * ND * 2);
  float* norms  = (float*)alloc(NB * 4);
  int*   order  = (int*)alloc(NB * 4);
  int*   pgroup = (int*)alloc(NB * 4);
  _Float16* f    = (_Float16*)alloc(NB * 2);
  _Float16* gpot = (_Float16*)alloc((size_t)NG * NB * 2);
  _Float16* fxx0 = (_Float16*)alloc(NB * 2);
  _Float16* fxx1 = (_Float16*)alloc(NB * 2);
  _Float16* fyy0 = (_Float16*)alloc(NB * 2);
  _Float16* fyy1 = (_Float16*)alloc(NB * 2);
  int*   counts = (int*)alloc(NG * 4);
  int*   starts = (int*)alloc((NG + 1) * 4);
  float* lc2    = (float*)alloc(NG * 4);
  unsigned int* cmax = (unsigned int*)alloc(4);

  k_setup<<<1, 256, 0, stream>>>(sub, order, pgroup, counts, starts, lc2, cmax,
                                 gpot, f, fxx0, fyy0);
  k_permute<<<NB, 128, 0, stream>>>(X, order, Xhi, Xlo, norms);
  k_gemm<<<dim3(16, 16), 256, 0, stream>>>(Xhi, Xlo, norms, C, cmax);
  for (int it = 0; it < NITER; ++it) {
    _Float16* fxi = (it & 1) ? fxx1 : fxx0;
    _Float16* fxo = (it & 1) ? fxx0 : fxx1;
    _Float16* fyi = (it & 1) ? fyy1 : fyy0;
    _Float16* fyo = (it & 1) ? fyy0 : fyy1;
    k_pass1<<<NB, 256, 0, stream>>>(C, gpot, fxi, fyi, f, fxo, fyo,
                                    pgroup, starts, lc2, cmax, it);
    k_pass2<<<NB, 256, 0, stream>>>(C, f, gpot, starts, lc2, cmax, it);
  }
  // after it=63 (odd), outputs landed in fxx0 / fyy0
  k_final<<<1, 256, 0, stream>>>(f, gpot, fxx0, fyy0, counts, starts, (float*)d_out);
}